// Round 9
// baseline (127.707 us; speedup 1.0000x reference)
//
#include <hip/hip_runtime.h>
#include <hip/hip_bf16.h>

#define B_SZ 8192
#define D_SZ 256
#define NTILES 2080   // (8192/128)*(8192/128+1)/2 upper-tri tiles
#define GRID_SIM 512  // persistent, 2 blocks/CU (65 KB LDS)
// rows pre-scaled by sqrt(log2(e)/T): exp2(acc) == exp(sim/T)
#define PRESCALE 4.539816004686735f
#define RING_U 8192   // ushorts per ring slot (A 8KB + B 8KB)

typedef __attribute__((ext_vector_type(4))) float f32x4;
typedef __attribute__((ext_vector_type(8))) short s16x8;

// ---------------- L2-normalize rows, scale, cast to bf16 (+ zero sums) -----
__global__ __launch_bounds__(256) void norm_kernel(const float* __restrict__ emb,
                                                   ushort* __restrict__ nbf,
                                                   float* __restrict__ sums) {
    // zero all_sum+pos_sum: 16384 floats over 256 blocks
    sums[blockIdx.x * 64 + (threadIdx.x >> 2)] = 0.0f;

    const int wave = threadIdx.x >> 6, lane = threadIdx.x & 63;
    for (int g = blockIdx.x; g < B_SZ / 4; g += 256) {
        const int row = g * 4 + wave;
        const float4 v = ((const float4*)(emb + (size_t)row * D_SZ))[lane];
        float ss = v.x * v.x + v.y * v.y + v.z * v.z + v.w * v.w;
        #pragma unroll
        for (int m = 1; m < 64; m <<= 1) ss += __shfl_xor(ss, m, 64);
        float s = PRESCALE / fmaxf(sqrtf(ss), 1e-12f);
        __hip_bfloat16 b0 = __float2bfloat16(v.x * s);
        __hip_bfloat16 b1 = __float2bfloat16(v.y * s);
        __hip_bfloat16 b2 = __float2bfloat16(v.z * s);
        __hip_bfloat16 b3 = __float2bfloat16(v.w * s);
        ushort4 o;
        o.x = *(ushort*)&b0; o.y = *(ushort*)&b1; o.z = *(ushort*)&b2; o.w = *(ushort*)&b3;
        ((ushort4*)(nbf + (size_t)row * D_SZ))[lane] = o;
    }
}

// ---------------- helpers ---------------------------------------------------
__device__ __forceinline__ void decode_tile(int tb, int& i0, int& j0, bool& diag) {
    int bj = (int)((sqrtf(8.0f * tb + 1.0f) - 1.0f) * 0.5f);
    while ((bj + 1) * (bj + 2) / 2 <= tb) ++bj;
    while (bj * (bj + 1) / 2 > tb) --bj;
    const int bi = tb - bj * (bj + 1) / 2;
    i0 = bi * 128; j0 = bj * 128; diag = (bi == bj);
}

// async global->LDS DMA, 16 B per lane. LDS dest = wave-uniform base +
// lane*16 (linear); swizzle lives in the per-lane GLOBAL address.
__device__ __forceinline__ void gload16(const ushort* g, ushort* l) {
    __builtin_amdgcn_global_load_lds(
        (const __attribute__((address_space(1))) unsigned int*)g,
        (__attribute__((address_space(3))) unsigned int*)l,
        16, 0, 0);
}

// One BK=32 stage of A+B staging: 4 DMAs per wave (2 A + 2 B).
// LDS rows are 32 ushorts (64 B = 4 chunks of 8). Lane l writes LDS row
// base+(l>>2), chunk l&3, sourcing global chunk (l&3)^((l>>2)&3) -- so LDS
// slot s of row R holds source chunk s^(R&3) (un-swizzled at read time).
// srcoff = (lane>>2)*D_SZ + ((lane&3)^((lane>>2)&3))*8, computed by caller.
__device__ __forceinline__ void issue_stage(ushort* sl,
                                            const ushort* __restrict__ N,
                                            int i0, int j0, int k0,
                                            int wave, int srcoff) {
    const ushort* gA = N + (size_t)(i0 + wave * 32) * D_SZ + k0 + srcoff;
    const ushort* gB = N + (size_t)(j0 + wave * 32) * D_SZ + k0 + srcoff;
    #pragma unroll
    for (int q = 0; q < 2; ++q) {
        gload16(gA + (size_t)(q * 16) * D_SZ, sl + (wave * 32 + q * 16) * 32);
        gload16(gB + (size_t)(q * 16) * D_SZ, sl + 4096 + (wave * 32 + q * 16) * 32);
    }
}

// ---------------- fused sim: ring-3 counted-vmcnt pipeline -----------------
// 8 stages of BK=32 per 128x128 tile, 3-slot LDS ring, prefetch distance 2.
// Per stage: s_waitcnt vmcnt(4) [stage-s DMAs done, stage-(s+1)'s stay IN
// FLIGHT] -> raw s_barrier -> issue stage s+2 -> ds_read + 16 MFMA.
// vmcnt ledger per wave (in-order drain): stage issues=4; epilogue atomics
// fixed at 8 col + 1 row -> stages 0,1 after an epilogue wait vmcnt(13).
__global__ __launch_bounds__(256) void sim_kernel(const ushort* __restrict__ N,
                                                  const int* __restrict__ ids,
                                                  float* __restrict__ all_sum,
                                                  float* __restrict__ pos_sum) {
    __shared__ ushort smem[3 * RING_U];     // ring: 3 x (A 8KB | B 8KB)
    __shared__ float pAll[128 * 17];        // partials, 17-padded
    __shared__ float pPos[128 * 17];

    const int t    = threadIdx.x;
    const int wave = t >> 6, lane = t & 63;
    const int wy   = wave >> 1, wx = wave & 1;
    const int hi   = lane >> 4, myc = lane & 15;
    const int srcoff = (lane >> 2) * D_SZ + (((lane & 3) ^ ((lane >> 2) & 3)) * 8);
    const int slot8  = (hi ^ (myc & 3)) * 8;   // un-swizzle for frag reads

    int tb = blockIdx.x;
    int i0, j0; bool diag;
    decode_tile(tb, i0, j0, diag);

    // prologue: stages 0,1 -> slots 0,1; one-time full drain
    issue_stage(smem,          N, i0, j0, 0,  wave, srcoff);
    issue_stage(smem + RING_U, N, i0, j0, 32, wave, srcoff);
    asm volatile("s_waitcnt vmcnt(0)" ::: "memory");

    int rc = 0;   // ring slot holding current stage's data

    while (true) {
        const int ntb = tb + GRID_SIM;
        const bool have_next = (ntb < NTILES);
        int ni0 = i0, nj0 = j0; bool ndiag = diag;
        if (have_next) decode_tile(ntb, ni0, nj0, ndiag);

        f32x4 acc[4][4];
        #pragma unroll
        for (int mi = 0; mi < 4; ++mi)
            #pragma unroll
            for (int ni = 0; ni < 4; ++ni)
                acc[mi][ni] = (f32x4){0.f, 0.f, 0.f, 0.f};

        #pragma unroll
        for (int s = 0; s < 8; ++s) {
            // counted wait: stage-s data landed; younger DMAs stay in flight
            if (s < 2)       asm volatile("s_waitcnt vmcnt(13)" ::: "memory");
            else if (s == 7) {
                if (have_next) asm volatile("s_waitcnt vmcnt(4)" ::: "memory");
                else           asm volatile("s_waitcnt vmcnt(0)" ::: "memory");
            } else           asm volatile("s_waitcnt vmcnt(4)" ::: "memory");
            __builtin_amdgcn_s_barrier();
            __builtin_amdgcn_sched_barrier(0);

            int ws = rc + 2; if (ws >= 3) ws -= 3;
            if (s < 6)           issue_stage(smem + ws * RING_U, N, i0, j0, (s + 2) * 32, wave, srcoff);
            else if (have_next)  issue_stage(smem + ws * RING_U, N, ni0, nj0, (s - 6) * 32, wave, srcoff);

            const ushort* sA = smem + rc * RING_U;
            const ushort* sB = sA + 4096;
            s16x8 af[4], bf[4];
            #pragma unroll
            for (int mi = 0; mi < 4; ++mi)
                af[mi] = *(const s16x8*)&sA[(wy * 64 + mi * 16 + myc) * 32 + slot8];
            #pragma unroll
            for (int ni = 0; ni < 4; ++ni)
                bf[ni] = *(const s16x8*)&sB[(wx * 64 + ni * 16 + myc) * 32 + slot8];
            #pragma unroll
            for (int mi = 0; mi < 4; ++mi)
                #pragma unroll
                for (int ni = 0; ni < 4; ++ni)
                    acc[mi][ni] = __builtin_amdgcn_mfma_f32_16x16x32_bf16(
                        af[mi], bf[ni], acc[mi][ni], 0, 0, 0);

            rc = rc + 1; if (rc >= 3) rc = 0;
        }

        // ---- epilogue.  C/D map: col=lane&15, row=hi*4+reg ----
        // Atomic instruction count is UNIFORM (8 col + 1 row per wave) so the
        // vmcnt ledger stays exact: diag contributions value-masked to 0.
        int idc[4];
        #pragma unroll
        for (int ni = 0; ni < 4; ++ni)
            idc[ni] = ids[j0 + wx * 64 + ni * 16 + myc];

        float cAll[4] = {0.f, 0.f, 0.f, 0.f};
        float cPos[4] = {0.f, 0.f, 0.f, 0.f};

        #pragma unroll
        for (int mi = 0; mi < 4; ++mi) {
            float rAll[4] = {0.f, 0.f, 0.f, 0.f};
            float rPos[4] = {0.f, 0.f, 0.f, 0.f};
            const int rbase = wy * 64 + mi * 16 + hi * 4;   // local row base
            const int4 idr  = *(const int4*)&ids[i0 + rbase];
            #pragma unroll
            for (int ni = 0; ni < 4; ++ni) {
                const int cloc = wx * 64 + ni * 16 + myc;   // local col
                #pragma unroll
                for (int rg = 0; rg < 4; ++rg) {
                    float e = __builtin_amdgcn_exp2f(acc[mi][ni][rg]);
                    if (diag && (rbase + rg) == cloc) e = 0.0f;   // diagonal
                    rAll[rg] += e; cAll[ni] += e;
                    const int idrv = (rg == 0) ? idr.x : (rg == 1) ? idr.y
                                   : (rg == 2) ? idr.z : idr.w;
                    if (idrv == idc[ni]) { rPos[rg] += e; cPos[ni] += e; }
                }
            }
            // fold adjacent col pairs (1 swizzle step), write 16 partials/row
            #pragma unroll
            for (int rg = 0; rg < 4; ++rg) {
                rAll[rg] += __shfl_xor(rAll[rg], 1, 64);
                rPos[rg] += __shfl_xor(rPos[rg], 1, 64);
            }
            if ((myc & 1) == 0) {
                const int slot = wx * 8 + (myc >> 1);       // 0..15
                #pragma unroll
                for (int rg = 0; rg < 4; ++rg) {
                    pAll[(rbase + rg) * 17 + slot] = rAll[rg];
                    pPos[(rbase + rg) * 17 + slot] = rPos[rg];
                }
            }
        }

        // column sums -> rows j via symmetry (value 0 on diag tiles; the
        // atomic is still ISSUED so per-wave vmcnt stays uniform at 8)
        #pragma unroll
        for (int ni = 0; ni < 4; ++ni) {
            cAll[ni] += __shfl_xor(cAll[ni], 16, 64);
            cAll[ni] += __shfl_xor(cAll[ni], 32, 64);
            cPos[ni] += __shfl_xor(cPos[ni], 16, 64);
            cPos[ni] += __shfl_xor(cPos[ni], 32, 64);
        }
        if (lane < 16) {
            #pragma unroll
            for (int ni = 0; ni < 4; ++ni) {
                const int gc = j0 + wx * 64 + ni * 16 + lane;
                atomicAdd(&all_sum[gc], diag ? 0.0f : cAll[ni]);
                atomicAdd(&pos_sum[gc], diag ? 0.0f : cPos[ni]);
            }
        }

        // partial writes visible to all waves; DMAs for next tile's stages
        // 0,1 remain IN FLIGHT across this barrier (lgkm-only drain)
        asm volatile("s_waitcnt lgkmcnt(0)" ::: "memory");
        __builtin_amdgcn_s_barrier();
        __builtin_amdgcn_sched_barrier(0);

        // row final reduce: thread t -> row t&127; 16 b32 reads, 17-stride
        {
            const int row = t & 127;
            const float* src = (t >= 128) ? pPos : pAll;
            float s = 0.0f;
            #pragma unroll
            for (int sl = 0; sl < 16; ++sl) s += src[row * 17 + sl];
            float* dst = (t >= 128) ? pos_sum : all_sum;
            atomicAdd(&dst[i0 + row], s);          // 1 VMEM instr per wave
        }
        // no vmcnt drain here: atomics (9/wave) are accounted in the next
        // tile's stage-0/1 waits (vmcnt 13 = 4 + 8col + 1row).

        if (!have_next) break;
        tb = ntb; i0 = ni0; j0 = nj0; diag = ndiag;
    }
}

// ---------------- final scalar reduce ----------------
__global__ __launch_bounds__(256) void loss_kernel(const float* __restrict__ all_sum,
                                                   const float* __restrict__ pos_sum,
                                                   float* __restrict__ out) {
    float loss = 0.0f, cnt = 0.0f;
    for (int i = threadIdx.x; i < B_SZ; i += 256) {
        float p = pos_sum[i], a = all_sum[i];
        if (p > 0.0f) { loss += logf(a) - logf(p); cnt += 1.0f; }
    }
    #pragma unroll
    for (int m = 1; m < 64; m <<= 1) {
        loss += __shfl_xor(loss, m, 64);
        cnt  += __shfl_xor(cnt, m, 64);
    }
    __shared__ float sl[4], sc[4];
    int wave = threadIdx.x >> 6, lane = threadIdx.x & 63;
    if (lane == 0) { sl[wave] = loss; sc[wave] = cnt; }
    __syncthreads();
    if (threadIdx.x == 0) {
        float L = sl[0] + sl[1] + sl[2] + sl[3];
        float C = sc[0] + sc[1] + sc[2] + sc[3];
        out[0] = L / fmaxf(C, 1.0f);
    }
}

extern "C" void kernel_launch(void* const* d_in, const int* in_sizes, int n_in,
                              void* d_out, int out_size, void* d_ws, size_t ws_size,
                              hipStream_t stream) {
    const float* emb = (const float*)d_in[0];
    const int*   ids = (const int*)d_in[1];
    float*       out = (float*)d_out;

    float*  all_sum = (float*)d_ws;
    float*  pos_sum = all_sum + B_SZ;
    ushort* nbf     = (ushort*)((char*)d_ws + 65536);   // 8192*256 bf16 = 4 MB

    norm_kernel<<<256, 256, 0, stream>>>(emb, nbf, all_sum);
    sim_kernel<<<GRID_SIM, 256, 0, stream>>>(nbf, ids, all_sum, pos_sum);
    loss_kernel<<<1, 256, 0, stream>>>(all_sum, pos_sum, out);
}